// Round 1
// baseline (247.139 us; speedup 1.0000x reference)
//
#include <hip/hip_runtime.h>

// Problem constants (match reference setup_inputs)
#define BB   32
#define CC   64
#define HH   80
#define WW   200
#define NPR  192
#define SS   36

// y0/y1/wy0/wy1 as a function of s only, replicating the reference fp32 op
// sequence:
//   k = sample_x_indexs[35-s] = floor((35-s)*71/35)   (exact in int arith)
//   pf = 1 - k/71 ; gy = pf*2-1 ; iy = ((gy+1)*0.5)*79
__device__ __forceinline__ void y_of_s(int s, int& y0, int& y1, float& wy0, float& wy1) {
    int k = ((35 - s) * 71) / 35;
    float pf = 1.0f - (float)k / 71.0f;
    float gy = pf * 2.0f - 1.0f;
    float iy = ((gy + 1.0f) * 0.5f) * 79.0f;
    float y0f = floorf(iy);
    y0 = (int)y0f;
    wy1 = iy - y0f;     // == 0 exactly when iy == 79, so clamped y1 is safe
    wy0 = 1.0f - wy1;
    y1 = y0 + 1;
    if (y1 > HH - 1) y1 = HH - 1;
    if (y0 < 0) y0 = 0;
}

// One block per (b, c). Stage the 72 needed (s,row) row-segments of this
// channel into LDS (coalesced float4 reads), then bilinear-gather from LDS.
__global__ __launch_bounds__(512, 4)
void pool_prior_kernel(const float* __restrict__ feat,
                       const float* __restrict__ prior_xs,
                       float* __restrict__ out) {
    __shared__ float lds_feat[72 * WW];   // [s][row01][x] : (s*2+row)*200 + x
    __shared__ float wy0_lut[SS];
    __shared__ float wy1_lut[SS];

    const int blk = blockIdx.x;
    const int b = blk >> 6;     // / 64
    const int c = blk & 63;     // % 64
    const int tid = threadIdx.x;

    // Per-s weight LUT (separate arrays -> stride-4B -> conflict-free reads)
    if (tid < SS) {
        int y0, y1; float wy0, wy1;
        y_of_s(tid, y0, y1, wy0, wy1);
        wy0_lut[tid] = wy0;
        wy1_lut[tid] = wy1;
    }

    // Stage: 72 segments x 200 floats = 3600 float4 loads, fully coalesced.
    const float* featc = feat + (size_t)(b * CC + c) * (HH * WW);
    #pragma unroll 1
    for (int idx = tid; idx < 72 * (WW / 4); idx += 512) {
        int seg = idx / 50;            // (s*2 + row)
        int off = idx - seg * 50;      // float4 index within row
        int s = seg >> 1;
        int row = seg & 1;
        int y0, y1; float wy0, wy1;
        y_of_s(s, y0, y1, wy0, wy1);
        int y = row ? y1 : y0;
        float4 v = *(const float4*)(featc + y * WW + off * 4);
        *(float4*)(&lds_feat[seg * WW + off * 4]) = v;
    }
    __syncthreads();

    const float* prior_b = prior_xs + (size_t)b * (NPR * SS);
    float* out_bc = out + (size_t)b * ((size_t)NPR * CC * SS) + (size_t)c * SS;

    // 6912 output elements for this (b,c); e = n*36 + s (same flat order as
    // prior_xs[b], so the prior load is perfectly coalesced).
    #pragma unroll 1
    for (int i = 0; i < (NPR * SS + 511) / 512; ++i) {
        int e = tid + i * 512;
        if (e < NPR * SS) {
            int n = e / SS;            // magic-mul
            int s = e - n * SS;
            float px = prior_b[e];
            // Replicate reference fp32 sequence: gx = px*2-1; ix = ((gx+1)*0.5)*199
            float gx = px * 2.0f - 1.0f;
            float ix = ((gx + 1.0f) * 0.5f) * (float)(WW - 1);
            float x0f = floorf(ix);
            int xi = (int)x0f;
            if (xi < 0) xi = 0;
            if (xi > WW - 2) xi = WW - 2;   // safety; unreachable for px in [0,1)
            float wx1 = ix - x0f;
            float wx0 = 1.0f - wx1;
            const float* p0 = &lds_feat[s * (2 * WW) + xi];
            float v00 = p0[0];
            float v01 = p0[1];
            float v10 = p0[WW];
            float v11 = p0[WW + 1];
            float wy0 = wy0_lut[s];
            float wy1 = wy1_lut[s];
            float r = wy0 * (wx0 * v00 + wx1 * v01)
                    + wy1 * (wx0 * v10 + wx1 * v11);
            out_bc[(size_t)n * (CC * SS) + s] = r;
        }
    }
}

extern "C" void kernel_launch(void* const* d_in, const int* in_sizes, int n_in,
                              void* d_out, int out_size, void* d_ws, size_t ws_size,
                              hipStream_t stream) {
    const float* feat  = (const float*)d_in[0];   // (32,64,80,200) fp32
    const float* prior = (const float*)d_in[1];   // (32,192,36)    fp32
    float* out = (float*)d_out;                   // (6144,64,36,1) fp32
    pool_prior_kernel<<<dim3(BB * CC), dim3(512), 0, stream>>>(feat, prior, out);
}

// Round 2
// 227.653 us; speedup vs baseline: 1.0856x; 1.0856x over previous
//
#include <hip/hip_runtime.h>

// Problem constants (match reference setup_inputs)
#define BB   32
#define CC   64
#define HH   80
#define WW   200
#define NPR  192
#define SS   36

// y0/y1/wy0/wy1 as a function of s only, replicating the reference fp32 op
// sequence:
//   k = sample_x_indexs[35-s] = floor((35-s)*71/35)   (exact in int arith)
//   pf = 1 - k/71 ; gy = pf*2-1 ; iy = ((gy+1)*0.5)*79
__device__ __forceinline__ void y_of_s(int s, int& y0, int& y1, float& wy0, float& wy1) {
    int k = ((35 - s) * 71) / 35;
    float pf = 1.0f - (float)k / 71.0f;
    float gy = pf * 2.0f - 1.0f;
    float iy = ((gy + 1.0f) * 0.5f) * 79.0f;
    float y0f = floorf(iy);
    y0 = (int)y0f;
    wy1 = iy - y0f;     // == 0 exactly when iy == 79, so clamped y1 is safe
    wy0 = 1.0f - wy1;
    y1 = y0 + 1;
    if (y1 > HH - 1) y1 = HH - 1;
    if (y0 < 0) y0 = 0;
}

// One block per (b, c). Stage the y-combined rows
//   comb[s][x] = wy0[s]*feat[y0[s]][x] + wy1[s]*feat[y1[s]][x]
// into LDS (28.8 KB -> 4 blocks/CU = 32 waves/CU), then each output element
// needs only one adjacent-pair LDS read + 1 fma pair.
__global__ __launch_bounds__(512, 8)
void pool_prior_kernel(const float* __restrict__ feat,
                       const float* __restrict__ prior_xs,
                       float* __restrict__ out) {
    __shared__ float comb[SS * WW];   // [s][x]

    const int blk = blockIdx.x;
    const int b = blk >> 6;     // / 64
    const int c = blk & 63;     // % 64
    const int tid = threadIdx.x;

    // Stage: 36 segments x 50 float4 = 1800 iterations, fully coalesced reads.
    const float* featc = feat + (size_t)(b * CC + c) * (HH * WW);
    #pragma unroll 1
    for (int idx = tid; idx < SS * (WW / 4); idx += 512) {
        int s = idx / 50;              // segment
        int off = (idx - s * 50) * 4;  // x offset
        int y0, y1; float wy0, wy1;
        y_of_s(s, y0, y1, wy0, wy1);
        float4 f0 = *(const float4*)(featc + y0 * WW + off);
        float4 f1 = *(const float4*)(featc + y1 * WW + off);
        float4 v;
        v.x = wy0 * f0.x + wy1 * f1.x;
        v.y = wy0 * f0.y + wy1 * f1.y;
        v.z = wy0 * f0.z + wy1 * f1.z;
        v.w = wy0 * f0.w + wy1 * f1.w;
        *(float4*)(&comb[s * WW + off]) = v;
    }
    __syncthreads();

    const float* prior_b = prior_xs + (size_t)b * (NPR * SS);
    float* out_bc = out + (size_t)b * ((size_t)NPR * CC * SS) + (size_t)c * SS;

    // 6912 output elements for this (b,c); e = n*36 + s (same flat order as
    // prior_xs[b], so the prior load is perfectly coalesced).
    // 6912 = 13*512 + 256: 13 full iterations + a half-wavefront tail.
    #pragma unroll 2
    for (int i = 0; i < 13; ++i) {
        int e = tid + i * 512;
        int n = e / SS;            // magic-mul
        int s = e - n * SS;
        float px = prior_b[e];
        float gx = px * 2.0f - 1.0f;
        float ix = ((gx + 1.0f) * 0.5f) * (float)(WW - 1);
        float x0f = floorf(ix);
        int xi = (int)x0f;
        if (xi < 0) xi = 0;
        if (xi > WW - 2) xi = WW - 2;   // unreachable for px in [0,1), safety
        float wx1 = ix - x0f;
        float wx0 = 1.0f - wx1;
        const float* p0 = &comb[s * WW + xi];
        float r = wx0 * p0[0] + wx1 * p0[1];
        out_bc[(size_t)n * (CC * SS) + s] = r;
    }
    {   // tail: e in [6656, 6912)
        int e = tid + 13 * 512;
        if (e < NPR * SS) {
            int n = e / SS;
            int s = e - n * SS;
            float px = prior_b[e];
            float gx = px * 2.0f - 1.0f;
            float ix = ((gx + 1.0f) * 0.5f) * (float)(WW - 1);
            float x0f = floorf(ix);
            int xi = (int)x0f;
            if (xi < 0) xi = 0;
            if (xi > WW - 2) xi = WW - 2;
            float wx1 = ix - x0f;
            float wx0 = 1.0f - wx1;
            const float* p0 = &comb[s * WW + xi];
            float r = wx0 * p0[0] + wx1 * p0[1];
            out_bc[(size_t)n * (CC * SS) + s] = r;
        }
    }
}

extern "C" void kernel_launch(void* const* d_in, const int* in_sizes, int n_in,
                              void* d_out, int out_size, void* d_ws, size_t ws_size,
                              hipStream_t stream) {
    const float* feat  = (const float*)d_in[0];   // (32,64,80,200) fp32
    const float* prior = (const float*)d_in[1];   // (32,192,36)    fp32
    float* out = (float*)d_out;                   // (6144,64,36,1) fp32
    pool_prior_kernel<<<dim3(BB * CC), dim3(512), 0, stream>>>(feat, prior, out);
}